// Round 10
// baseline (140.010 us; speedup 1.0000x reference)
//
#include <hip/hip_runtime.h>

#define N_NODES 50000
#define N_EDGES 1600000
#define IN_F 128
#define OUT_F 128   // HEADS*HEAD_DIM
#define HEADS 4
#define HEAD_DIM 32
#define NEG_SLOPE 0.2f

#define NB 391        // coarse buckets: bucket = dst >> 7 (128 nodes each)
#define CAP 4792      // per-bucket capacity (mean 4092, +10.9 sigma), %8==0
#define P1_EPT 16     // phase-1 edges per thread
#define P1_EPB (P1_EPT * 256)

typedef __attribute__((ext_vector_type(8))) short short8v;
typedef __attribute__((ext_vector_type(4))) float f32x4;

__device__ __forceinline__ unsigned short f2bf(float f) {
    unsigned u = __builtin_bit_cast(unsigned, f);
    u += 0x7FFFu + ((u >> 16) & 1u);   // round-to-nearest-even
    return (unsigned short)(u >> 16);
}
__device__ __forceinline__ float bf_lo(unsigned v) {
    return __builtin_bit_cast(float, v << 16);
}
__device__ __forceinline__ float bf_hi(unsigned v) {
    return __builtin_bit_cast(float, v & 0xFFFF0000u);
}

// ---------------------------------------------------------------------------
// Prep: W fp32 -> bf16 + init bucket cursors.
// ---------------------------------------------------------------------------
__global__ __launch_bounds__(256) void prep_kernel(
    const float* __restrict__ W, unsigned short* __restrict__ wbf,
    int* __restrict__ gcursor)
{
    int t = blockIdx.x * 256 + threadIdx.x;
    if (t < 16384) wbf[t] = f2bf(W[t]);
    if (t < NB) gcursor[t] = t * CAP;
}

// ---------------------------------------------------------------------------
// GEMM via MFMA: h = x @ W^T (bf16 in, fp32 accum, bf16 h out) with fused
// alpha epilogue. C/D mapping: col = nf*16 + (lane&15), row = (lane>>4)*4+reg.
// ---------------------------------------------------------------------------
__global__ __launch_bounds__(256) void gemm_mfma_kernel(
    const float* __restrict__ x, const unsigned short* __restrict__ wbf,
    const float* __restrict__ a,
    unsigned short* __restrict__ hb,
    float* __restrict__ alpha_s, float* __restrict__ alpha_d)
{
    const int tid = threadIdx.x;
    const int wave = tid >> 6;
    const int lane = tid & 63;
    const int lr = lane & 15;
    const int lg = lane >> 4;
    const int nodeA = blockIdx.x * 64 + wave * 16 + lr;
    const int nrow = nodeA < N_NODES ? nodeA : 0;

    f32x4 acc[8];
    #pragma unroll
    for (int i = 0; i < 8; ++i) acc[i] = (f32x4){0.f, 0.f, 0.f, 0.f};

    #pragma unroll
    for (int ks = 0; ks < 4; ++ks) {
        const float* xp = x + (size_t)nrow * 128 + ks * 32 + lg * 8;
        float4 xa = *(const float4*)xp;
        float4 xc = *(const float4*)(xp + 4);
        short8v afrag;
        afrag[0] = (short)f2bf(xa.x); afrag[1] = (short)f2bf(xa.y);
        afrag[2] = (short)f2bf(xa.z); afrag[3] = (short)f2bf(xa.w);
        afrag[4] = (short)f2bf(xc.x); afrag[5] = (short)f2bf(xc.y);
        afrag[6] = (short)f2bf(xc.z); afrag[7] = (short)f2bf(xc.w);
        #pragma unroll
        for (int nf = 0; nf < 8; ++nf) {
            const short8v bfrag = *(const short8v*)(wbf + (size_t)(nf * 16 + lr) * 128 + ks * 32 + lg * 8);
            acc[nf] = __builtin_amdgcn_mfma_f32_16x16x32_bf16(afrag, bfrag, acc[nf], 0, 0, 0);
        }
    }

    float as_c[8], ad_c[8];
    #pragma unroll
    for (int nf = 0; nf < 8; ++nf) {
        const int idx = (nf >> 1) * 64 + (nf & 1) * 16 + lr;
        as_c[nf] = a[idx];
        ad_c[nf] = a[idx + 32];
    }

    const int nbase = blockIdx.x * 64 + wave * 16 + lg * 4;
    #pragma unroll
    for (int reg = 0; reg < 4; ++reg) {
        const int n2 = nbase + reg;
        if (n2 < N_NODES) {
            unsigned short* hp = hb + (size_t)n2 * 128 + lr;
            #pragma unroll
            for (int nf = 0; nf < 8; ++nf)
                hp[nf * 16] = f2bf(acc[nf][reg]);
        }
        float sh[4], th[4];
        #pragma unroll
        for (int hd = 0; hd < 4; ++hd) {
            sh[hd] = acc[2 * hd][reg] * as_c[2 * hd] + acc[2 * hd + 1][reg] * as_c[2 * hd + 1];
            th[hd] = acc[2 * hd][reg] * ad_c[2 * hd] + acc[2 * hd + 1][reg] * ad_c[2 * hd + 1];
        }
        #pragma unroll
        for (int off = 8; off >= 1; off >>= 1) {
            #pragma unroll
            for (int hd = 0; hd < 4; ++hd) {
                sh[hd] += __shfl_xor(sh[hd], off);
                th[hd] += __shfl_xor(th[hd], off);
            }
        }
        if (lr == 0 && n2 < N_NODES) {
            #pragma unroll
            for (int hd = 0; hd < 4; ++hd) {
                alpha_s[n2 * 4 + hd] = sh[hd];
                alpha_d[n2 * 4 + hd] = th[hd];
            }
        }
    }
}

// ---------------------------------------------------------------------------
// Phase 1: partition edges into NB coarse buckets (bucket = dst>>7).
// ---------------------------------------------------------------------------
__global__ __launch_bounds__(256) void part_kernel(
    const int* __restrict__ ei, int* __restrict__ gcursor,
    unsigned* __restrict__ part)
{
    __shared__ int cnt[NB];
    __shared__ int gbase[NB];
    const int tid = threadIdx.x;
    const int e0 = blockIdx.x * P1_EPB;

    for (int i = tid; i < NB; i += 256) cnt[i] = 0;
    __syncthreads();

    unsigned pk[P1_EPT];
    int bk[P1_EPT];
    int loc[P1_EPT];
    #pragma unroll
    for (int c4 = 0; c4 < P1_EPT / 4; ++c4) {
        int e = e0 + c4 * 1024 + tid * 4;
        if (e < N_EDGES) {
            int4 s4 = *(const int4*)(ei + e);
            int4 d4 = *(const int4*)(ei + N_EDGES + e);
            int ss[4] = {s4.x, s4.y, s4.z, s4.w};
            int dd[4] = {d4.x, d4.y, d4.z, d4.w};
            #pragma unroll
            for (int j = 0; j < 4; ++j) {
                int k = c4 * 4 + j;
                int bb = dd[j] >> 7;
                bk[k] = bb;
                pk[k] = ((unsigned)(dd[j] & 127) << 16) | (unsigned)ss[j];
                loc[k] = atomicAdd(&cnt[bb], 1);
            }
        } else {
            #pragma unroll
            for (int j = 0; j < 4; ++j) bk[c4 * 4 + j] = -1;
        }
    }
    __syncthreads();
    for (int bq = tid; bq < NB; bq += 256)
        gbase[bq] = atomicAdd(&gcursor[bq], cnt[bq]);
    __syncthreads();
    #pragma unroll
    for (int k = 0; k < P1_EPT; ++k)
        if (bk[k] >= 0)
            part[gbase[bk[k]] + loc[k]] = pk[k];
}

// ---------------------------------------------------------------------------
// Phase 2: one block per bucket. (1) stage + histogram, (2) scan, (3) LDS
// scatter of FULL (ln|src) dwords to sorted order, (4) STREAMING pass:
// compute per-edge att (bf16 x4) + write att01/att23/srcs16 fully coalesced.
// att01 aliases part[] (all part reads for this bucket done at stage 1).
// ---------------------------------------------------------------------------
__global__ __launch_bounds__(256) void bucket_kernel(
    const int* __restrict__ gcursor, const unsigned* __restrict__ part,
    unsigned short* __restrict__ srcs16,
    unsigned* __restrict__ att01, unsigned* __restrict__ att23,
    const float4* __restrict__ as4, const float4* __restrict__ ad4,
    int* __restrict__ node_start, int* __restrict__ node_cnt)
{
    __shared__ unsigned ent[CAP];
    __shared__ unsigned srt[CAP];
    __shared__ int cnt4[4][128];
    __shared__ int sc[128];
    __shared__ int cur4[4][128];

    const int b = blockIdx.x;
    const int tid = threadIdx.x;
    const int w = tid >> 6;
    const int bstart = b * CAP;
    int n_b = gcursor[b] - bstart;
    if (n_b > CAP) n_b = CAP;

    if (tid < 128) {
        cnt4[0][tid] = 0; cnt4[1][tid] = 0; cnt4[2][tid] = 0; cnt4[3][tid] = 0;
    }
    __syncthreads();

    for (int i = tid; i < n_b; i += 256) {
        unsigned e = part[bstart + i];
        ent[i] = e;
        atomicAdd(&cnt4[w][e >> 16], 1);
    }
    __syncthreads();   // all part reads done -> att01 may alias part

    int c = 0;
    if (tid < 128) {
        c = cnt4[0][tid] + cnt4[1][tid] + cnt4[2][tid] + cnt4[3][tid];
        sc[tid] = c;
    }
    __syncthreads();
    #pragma unroll
    for (int off = 1; off < 128; off <<= 1) {
        int v = 0;
        if (tid < 128 && tid >= off) v = sc[tid - off];
        __syncthreads();
        if (tid < 128) sc[tid] += v;
        __syncthreads();
    }
    if (tid < 128) {
        int eb = sc[tid] - c;
        int c0 = cnt4[0][tid], c1 = cnt4[1][tid], c2 = cnt4[2][tid];
        cur4[0][tid] = eb;
        cur4[1][tid] = eb + c0;
        cur4[2][tid] = eb + c0 + c1;
        cur4[3][tid] = eb + c0 + c1 + c2;
        const int node = b * 128 + tid;
        if (node < N_NODES) {
            node_start[node] = bstart + eb;
            node_cnt[node] = c;
        }
    }
    __syncthreads();

    for (int i = tid; i < n_b; i += 256) {
        unsigned e = ent[i];
        int loc = atomicAdd(&cur4[w][e >> 16], 1);
        srt[loc] = e;                       // full (ln|src) dword
    }
    __syncthreads();

    // streaming att + writeout pass: consecutive i -> coalesced stores
    for (int i = tid; i < n_b; i += 256) {
        unsigned e = srt[i];
        unsigned srcid = e & 0xFFFFu;
        unsigned ln = e >> 16;
        float4 sv = as4[srcid];
        float4 dv = ad4[b * 128 + ln];
        float t0 = sv.x + dv.x, t1 = sv.y + dv.y, t2 = sv.z + dv.z, t3 = sv.w + dv.w;
        t0 = t0 > 0.f ? t0 : NEG_SLOPE * t0;
        t1 = t1 > 0.f ? t1 : NEG_SLOPE * t1;
        t2 = t2 > 0.f ? t2 : NEG_SLOPE * t2;
        t3 = t3 > 0.f ? t3 : NEG_SLOPE * t3;
        att01[bstart + i] = (unsigned)f2bf(t0) | ((unsigned)f2bf(t1) << 16);
        att23[bstart + i] = (unsigned)f2bf(t2) | ((unsigned)f2bf(t3) << 16);
        srcs16[bstart + i] = (unsigned short)srcid;
    }
}

// ---------------------------------------------------------------------------
// Gather: one wave per dst node, lane owns features (2*lane, 2*lane+1).
// Vectorized broadcast streams: per 8 edges 1x int4 (src ids) + 4x uint2
// (att dwords; lane selects its bf16 half) + 8 h loads + 16 fma.
// Unrolled loop runs on absolute-8-aligned i (bstart%8==0 -> 16B alignment).
// ---------------------------------------------------------------------------
__global__ __launch_bounds__(256) void gather_kernel(
    const unsigned short* __restrict__ srcs,
    const int* __restrict__ node_start, const int* __restrict__ node_cnt,
    const unsigned* __restrict__ h32,
    const unsigned* __restrict__ att01, const unsigned* __restrict__ att23,
    float* __restrict__ out)
{
    const int wid = (blockIdx.x * 256 + threadIdx.x) >> 6;
    if (wid >= N_NODES) return;
    const unsigned lane = threadIdx.x & 63;
    const unsigned start = (unsigned)node_start[wid];
    const unsigned end = start + (unsigned)node_cnt[wid];
    const unsigned hsel = (lane >> 4) & 1;          // odd head -> high half
    const unsigned shl = hsel ? 0 : 16;
    const unsigned* __restrict__ ab32 = (lane & 32) ? att23 : att01;

    float a0x = 0.f, a0y = 0.f, a1x = 0.f, a1y = 0.f;
    float a2x = 0.f, a2y = 0.f, a3x = 0.f, a3y = 0.f;

    unsigned i = start;
    unsigned ia = (start + 7u) & ~7u;
    if (ia > end) ia = end;
    for (; i < ia; ++i) {                           // scalar prologue to align
        unsigned s0 = srcs[i];
        float t0 = __builtin_bit_cast(float, (ab32[i] << shl) & 0xFFFF0000u);
        unsigned v0 = h32[(s0 << 6) | lane];
        a0x = fmaf(t0, bf_lo(v0), a0x); a0y = fmaf(t0, bf_hi(v0), a0y);
    }
    for (; i + 8 <= end; i += 8) {
        int4 sp = *(const int4*)(srcs + i);         // 8 src ids
        unsigned w0 = (unsigned)sp.x, w1 = (unsigned)sp.y;
        unsigned w2 = (unsigned)sp.z, w3 = (unsigned)sp.w;
        uint2 p0 = *(const uint2*)(ab32 + i);
        uint2 p1 = *(const uint2*)(ab32 + i + 2);
        uint2 p2 = *(const uint2*)(ab32 + i + 4);
        uint2 p3 = *(const uint2*)(ab32 + i + 6);
        unsigned s0 = w0 & 0xFFFFu, s1 = w0 >> 16;
        unsigned s2 = w1 & 0xFFFFu, s3 = w1 >> 16;
        unsigned s4 = w2 & 0xFFFFu, s5 = w2 >> 16;
        unsigned s6 = w3 & 0xFFFFu, s7 = w3 >> 16;
        float t0 = __builtin_bit_cast(float, (p0.x << shl) & 0xFFFF0000u);
        float t1 = __builtin_bit_cast(float, (p0.y << shl) & 0xFFFF0000u);
        float t2 = __builtin_bit_cast(float, (p1.x << shl) & 0xFFFF0000u);
        float t3 = __builtin_bit_cast(float, (p1.y << shl) & 0xFFFF0000u);
        float t4 = __builtin_bit_cast(float, (p2.x << shl) & 0xFFFF0000u);
        float t5 = __builtin_bit_cast(float, (p2.y << shl) & 0xFFFF0000u);
        float t6 = __builtin_bit_cast(float, (p3.x << shl) & 0xFFFF0000u);
        float t7 = __builtin_bit_cast(float, (p3.y << shl) & 0xFFFF0000u);
        unsigned v0 = h32[(s0 << 6) | lane];
        unsigned v1 = h32[(s1 << 6) | lane];
        unsigned v2 = h32[(s2 << 6) | lane];
        unsigned v3 = h32[(s3 << 6) | lane];
        unsigned v4 = h32[(s4 << 6) | lane];
        unsigned v5 = h32[(s5 << 6) | lane];
        unsigned v6 = h32[(s6 << 6) | lane];
        unsigned v7 = h32[(s7 << 6) | lane];
        a0x = fmaf(t0, bf_lo(v0), a0x); a0y = fmaf(t0, bf_hi(v0), a0y);
        a1x = fmaf(t1, bf_lo(v1), a1x); a1y = fmaf(t1, bf_hi(v1), a1y);
        a2x = fmaf(t2, bf_lo(v2), a2x); a2y = fmaf(t2, bf_hi(v2), a2y);
        a3x = fmaf(t3, bf_lo(v3), a3x); a3y = fmaf(t3, bf_hi(v3), a3y);
        a0x = fmaf(t4, bf_lo(v4), a0x); a0y = fmaf(t4, bf_hi(v4), a0y);
        a1x = fmaf(t5, bf_lo(v5), a1x); a1y = fmaf(t5, bf_hi(v5), a1y);
        a2x = fmaf(t6, bf_lo(v6), a2x); a2y = fmaf(t6, bf_hi(v6), a2y);
        a3x = fmaf(t7, bf_lo(v7), a3x); a3y = fmaf(t7, bf_hi(v7), a3y);
    }
    for (; i < end; ++i) {                          // scalar tail
        unsigned s0 = srcs[i];
        float t0 = __builtin_bit_cast(float, (ab32[i] << shl) & 0xFFFF0000u);
        unsigned v0 = h32[(s0 << 6) | lane];
        a1x = fmaf(t0, bf_lo(v0), a1x); a1y = fmaf(t0, bf_hi(v0), a1y);
    }
    float2 r = {(a0x + a1x) + (a2x + a3x), (a0y + a1y) + (a2y + a3y)};
    ((float2*)out)[(unsigned)wid * 64 + lane] = r;
}

// ---------------------------------------------------------------------------
// Fallback atomic edge kernel (only if ws_size too small for the sort path).
// ---------------------------------------------------------------------------
__global__ __launch_bounds__(256) void edge_kernel(
    const int* __restrict__ ei,
    const unsigned* __restrict__ h32,
    const float* __restrict__ alpha_s, const float* __restrict__ alpha_d,
    float* __restrict__ out)
{
    const unsigned total = (unsigned)N_EDGES * 32u;
    const unsigned stride = gridDim.x * blockDim.x;
    for (unsigned i = blockIdx.x * blockDim.x + threadIdx.x; i < total; i += stride) {
        const int e = (int)(i >> 5);
        const int c = (int)(i & 31);
        const int src = ei[e];
        const int dst = ei[N_EDGES + e];
        const int head = c >> 3;

        float att = alpha_s[src * 4 + head] + alpha_d[dst * 4 + head];
        att = att > 0.f ? att : NEG_SLOPE * att;

        unsigned v0 = h32[(size_t)src * 64 + c * 2];
        unsigned v1 = h32[(size_t)src * 64 + c * 2 + 1];
        float* po = out + (size_t)dst * 128 + c * 4;
        atomicAdd(po + 0, att * bf_lo(v0));
        atomicAdd(po + 1, att * bf_hi(v0));
        atomicAdd(po + 2, att * bf_lo(v1));
        atomicAdd(po + 3, att * bf_hi(v1));
    }
}

extern "C" void kernel_launch(void* const* d_in, const int* in_sizes, int n_in,
                              void* d_out, int out_size, void* d_ws, size_t ws_size,
                              hipStream_t stream) {
    const float* x  = (const float*)d_in[0];
    const int*   ei = (const int*)d_in[1];
    const float* W  = (const float*)d_in[2];
    const float* a  = (const float*)d_in[3];
    float* out = (float*)d_out;

    // Workspace layout (~33.5 MB total):
    //   hb      12.8 MB | alpha_s/d 1.6 MB | part(=att01) 7.49 MB |
    //   srcs16  3.75 MB | att23 7.49 MB | gcursor/node arrays 0.4 MB | wbf 32KB
    unsigned short* hb = (unsigned short*)d_ws;
    float* as = (float*)(hb + (size_t)N_NODES * 128);
    float* ad = as + (size_t)N_NODES * 4;
    unsigned* part = (unsigned*)(ad + (size_t)N_NODES * 4);
    unsigned short* srcs16 = (unsigned short*)(part + (size_t)NB * CAP);
    unsigned* att23 = (unsigned*)(srcs16 + (size_t)NB * CAP);
    int* gcursor = (int*)(att23 + (size_t)NB * CAP);
    int* node_start = gcursor + 512;
    int* node_cnt   = node_start + 50176;
    unsigned short* wbf = (unsigned short*)(node_cnt + 50176);
    const size_t needed = (size_t)((char*)(wbf + 16384) - (char*)d_ws);

    prep_kernel<<<64, 256, 0, stream>>>(W, wbf, gcursor);
    gemm_mfma_kernel<<<(N_NODES + 63) / 64, 256, 0, stream>>>(x, wbf, a, hb, as, ad);

    if (ws_size >= needed) {
        part_kernel<<<(N_EDGES + P1_EPB - 1) / P1_EPB, 256, 0, stream>>>(ei, gcursor, part);
        bucket_kernel<<<NB, 256, 0, stream>>>(
            gcursor, part, srcs16, /*att01=*/part, att23,
            (const float4*)as, (const float4*)ad, node_start, node_cnt);
        gather_kernel<<<(N_NODES * 64 + 255) / 256, 256, 0, stream>>>(
            srcs16, node_start, node_cnt, (const unsigned*)hb,
            /*att01=*/part, att23, out);
    } else {
        hipMemsetAsync(d_out, 0, (size_t)out_size * sizeof(float), stream);
        edge_kernel<<<4096, 256, 0, stream>>>(ei, (const unsigned*)hb, as, ad, out);
    }
}

// Round 11
// 106.319 us; speedup vs baseline: 1.3169x; 1.3169x over previous
//
#include <hip/hip_runtime.h>

#define N_NODES 50000
#define N_EDGES 1600000
#define IN_F 128
#define OUT_F 128   // HEADS*HEAD_DIM
#define HEADS 4
#define HEAD_DIM 32
#define NEG_SLOPE 0.2f

#define NB 391        // coarse buckets: bucket = dst >> 7 (128 nodes each)
#define CAP 4800      // per-bucket capacity (mean 4092, +11 sigma)
#define P1_EPT 16     // phase-1 edges per thread
#define P1_EPB (P1_EPT * 256)
#define GEMM_BLOCKS ((N_NODES + 63) / 64)            // 782
#define PART_BLOCKS ((N_EDGES + P1_EPB - 1) / P1_EPB) // 391

typedef __attribute__((ext_vector_type(8))) short short8v;
typedef __attribute__((ext_vector_type(4))) float f32x4;

__device__ __forceinline__ unsigned short f2bf(float f) {
    unsigned u = __builtin_bit_cast(unsigned, f);
    u += 0x7FFFu + ((u >> 16) & 1u);   // round-to-nearest-even
    return (unsigned short)(u >> 16);
}
__device__ __forceinline__ float bf_lo(unsigned v) {
    return __builtin_bit_cast(float, v << 16);
}
__device__ __forceinline__ float bf_hi(unsigned v) {
    return __builtin_bit_cast(float, v & 0xFFFF0000u);
}

// ---------------------------------------------------------------------------
// Prep: W fp32 -> bf16 + init bucket cursors (must precede the fused kernel).
// ---------------------------------------------------------------------------
__global__ __launch_bounds__(256) void prep_kernel(
    const float* __restrict__ W, unsigned short* __restrict__ wbf,
    int* __restrict__ gcursor)
{
    int t = blockIdx.x * 256 + threadIdx.x;
    if (t < 16384) wbf[t] = f2bf(W[t]);
    if (t < NB) gcursor[t] = t * CAP;
}

// ---------------------------------------------------------------------------
// Fused kernel: blocks [0, GEMM_BLOCKS) run the MFMA gemm+alpha path;
// blocks [GEMM_BLOCKS, GEMM_BLOCKS+PART_BLOCKS) run the edge-partition path.
// The two are data-independent; fusing them overlaps MFMA-bound gemm with
// the LDS-atomic/latency-bound partition on the same dispatch.
// ---------------------------------------------------------------------------
__global__ __launch_bounds__(256) void fused_gp_kernel(
    const float* __restrict__ x, const unsigned short* __restrict__ wbf,
    const float* __restrict__ a,
    unsigned short* __restrict__ hb,
    float* __restrict__ alpha_s, float* __restrict__ alpha_d,
    const int* __restrict__ ei, int* __restrict__ gcursor,
    unsigned* __restrict__ part)
{
    __shared__ int cnt[NB];
    __shared__ int gbase[NB];

    const int tid = threadIdx.x;

    if (blockIdx.x < GEMM_BLOCKS) {
        // ---------------- GEMM + alpha path ----------------
        const int wave = tid >> 6;
        const int lane = tid & 63;
        const int lr = lane & 15;
        const int lg = lane >> 4;
        const int nodeA = blockIdx.x * 64 + wave * 16 + lr;
        const int nrow = nodeA < N_NODES ? nodeA : 0;

        f32x4 acc[8];
        #pragma unroll
        for (int i = 0; i < 8; ++i) acc[i] = (f32x4){0.f, 0.f, 0.f, 0.f};

        #pragma unroll
        for (int ks = 0; ks < 4; ++ks) {
            const float* xp = x + (size_t)nrow * 128 + ks * 32 + lg * 8;
            float4 xa = *(const float4*)xp;
            float4 xc = *(const float4*)(xp + 4);
            short8v afrag;
            afrag[0] = (short)f2bf(xa.x); afrag[1] = (short)f2bf(xa.y);
            afrag[2] = (short)f2bf(xa.z); afrag[3] = (short)f2bf(xa.w);
            afrag[4] = (short)f2bf(xc.x); afrag[5] = (short)f2bf(xc.y);
            afrag[6] = (short)f2bf(xc.z); afrag[7] = (short)f2bf(xc.w);
            #pragma unroll
            for (int nf = 0; nf < 8; ++nf) {
                const short8v bfrag = *(const short8v*)(wbf + (size_t)(nf * 16 + lr) * 128 + ks * 32 + lg * 8);
                acc[nf] = __builtin_amdgcn_mfma_f32_16x16x32_bf16(afrag, bfrag, acc[nf], 0, 0, 0);
            }
        }

        float as_c[8], ad_c[8];
        #pragma unroll
        for (int nf = 0; nf < 8; ++nf) {
            const int idx = (nf >> 1) * 64 + (nf & 1) * 16 + lr;
            as_c[nf] = a[idx];
            ad_c[nf] = a[idx + 32];
        }

        const int nbase = blockIdx.x * 64 + wave * 16 + lg * 4;
        #pragma unroll
        for (int reg = 0; reg < 4; ++reg) {
            const int n2 = nbase + reg;
            if (n2 < N_NODES) {
                unsigned short* hp = hb + (size_t)n2 * 128 + lr;
                #pragma unroll
                for (int nf = 0; nf < 8; ++nf)
                    hp[nf * 16] = f2bf(acc[nf][reg]);
            }
            float sh[4], th[4];
            #pragma unroll
            for (int hd = 0; hd < 4; ++hd) {
                sh[hd] = acc[2 * hd][reg] * as_c[2 * hd] + acc[2 * hd + 1][reg] * as_c[2 * hd + 1];
                th[hd] = acc[2 * hd][reg] * ad_c[2 * hd] + acc[2 * hd + 1][reg] * ad_c[2 * hd + 1];
            }
            #pragma unroll
            for (int off = 8; off >= 1; off >>= 1) {
                #pragma unroll
                for (int hd = 0; hd < 4; ++hd) {
                    sh[hd] += __shfl_xor(sh[hd], off);
                    th[hd] += __shfl_xor(th[hd], off);
                }
            }
            if (lr == 0 && n2 < N_NODES) {
                #pragma unroll
                for (int hd = 0; hd < 4; ++hd) {
                    alpha_s[n2 * 4 + hd] = sh[hd];
                    alpha_d[n2 * 4 + hd] = th[hd];
                }
            }
        }
    } else {
        // ---------------- edge partition path ----------------
        const int e0 = (blockIdx.x - GEMM_BLOCKS) * P1_EPB;

        for (int i = tid; i < NB; i += 256) cnt[i] = 0;
        __syncthreads();

        unsigned pk[P1_EPT];
        int bk[P1_EPT];
        int loc[P1_EPT];
        #pragma unroll
        for (int c4 = 0; c4 < P1_EPT / 4; ++c4) {
            int e = e0 + c4 * 1024 + tid * 4;
            if (e < N_EDGES) {
                int4 s4 = *(const int4*)(ei + e);
                int4 d4 = *(const int4*)(ei + N_EDGES + e);
                int ss[4] = {s4.x, s4.y, s4.z, s4.w};
                int dd[4] = {d4.x, d4.y, d4.z, d4.w};
                #pragma unroll
                for (int j = 0; j < 4; ++j) {
                    int k = c4 * 4 + j;
                    int bb = dd[j] >> 7;
                    bk[k] = bb;
                    pk[k] = ((unsigned)(dd[j] & 127) << 16) | (unsigned)ss[j];
                    loc[k] = atomicAdd(&cnt[bb], 1);
                }
            } else {
                #pragma unroll
                for (int j = 0; j < 4; ++j) bk[c4 * 4 + j] = -1;
            }
        }
        __syncthreads();
        for (int bq = tid; bq < NB; bq += 256)
            gbase[bq] = atomicAdd(&gcursor[bq], cnt[bq]);
        __syncthreads();
        #pragma unroll
        for (int k = 0; k < P1_EPT; ++k)
            if (bk[k] >= 0)
                part[gbase[bk[k]] + loc[k]] = pk[k];
    }
}

// ---------------------------------------------------------------------------
// Phase 2: one block per bucket (391 blocks, 128 nodes each). Per-wave
// histograms + cursors cut LDS-atomic contention 4x.
// ---------------------------------------------------------------------------
__global__ __launch_bounds__(256) void bucket_kernel(
    const int* __restrict__ gcursor, const unsigned* __restrict__ part,
    unsigned short* __restrict__ srcs16,
    int* __restrict__ node_start, int* __restrict__ node_cnt)
{
    __shared__ unsigned ent[CAP];
    __shared__ unsigned short srt[CAP];
    __shared__ int cnt4[4][128];
    __shared__ int sc[128];
    __shared__ int cur4[4][128];

    const int b = blockIdx.x;
    const int tid = threadIdx.x;
    const int w = tid >> 6;
    const int bstart = b * CAP;
    int n_b = gcursor[b] - bstart;
    if (n_b > CAP) n_b = CAP;

    if (tid < 128) {
        cnt4[0][tid] = 0; cnt4[1][tid] = 0; cnt4[2][tid] = 0; cnt4[3][tid] = 0;
    }
    __syncthreads();

    for (int i = tid; i < n_b; i += 256) {
        unsigned e = part[bstart + i];
        ent[i] = e;
        atomicAdd(&cnt4[w][e >> 16], 1);
    }
    __syncthreads();

    int c = 0;
    if (tid < 128) {
        c = cnt4[0][tid] + cnt4[1][tid] + cnt4[2][tid] + cnt4[3][tid];
        sc[tid] = c;
    }
    __syncthreads();
    #pragma unroll
    for (int off = 1; off < 128; off <<= 1) {
        int v = 0;
        if (tid < 128 && tid >= off) v = sc[tid - off];
        __syncthreads();
        if (tid < 128) sc[tid] += v;
        __syncthreads();
    }
    if (tid < 128) {
        int eb = sc[tid] - c;
        int c0 = cnt4[0][tid], c1 = cnt4[1][tid], c2 = cnt4[2][tid];
        cur4[0][tid] = eb;
        cur4[1][tid] = eb + c0;
        cur4[2][tid] = eb + c0 + c1;
        cur4[3][tid] = eb + c0 + c1 + c2;
        const int node = b * 128 + tid;
        if (node < N_NODES) {
            node_start[node] = bstart + eb;
            node_cnt[node] = c;
        }
    }
    __syncthreads();

    for (int i = tid; i < n_b; i += 256) {
        unsigned e = ent[i];
        int loc = atomicAdd(&cur4[w][e >> 16], 1);
        srt[loc] = (unsigned short)(e & 0xFFFFu);
    }
    __syncthreads();

    const unsigned* srt32 = (const unsigned*)srt;
    unsigned* dst32 = (unsigned*)(srcs16 + bstart);
    const int nw2 = (n_b + 1) >> 1;
    for (int i = tid; i < nw2; i += 256) dst32[i] = srt32[i];
}

// ---------------------------------------------------------------------------
// Gather: one wave per dst node, lane owns features (2*lane, 2*lane+1).
// 8 independent scalar src loads per iter -> 8 h-load chains in flight.
// ---------------------------------------------------------------------------
__global__ __launch_bounds__(256) void gather_kernel(
    const unsigned short* __restrict__ srcs,
    const int* __restrict__ node_start, const int* __restrict__ node_cnt,
    const unsigned* __restrict__ h32,
    const float* __restrict__ alpha_s, const float* __restrict__ alpha_d,
    float* __restrict__ out)
{
    const int wid = (blockIdx.x * 256 + threadIdx.x) >> 6;
    if (wid >= N_NODES) return;
    const int lane = threadIdx.x & 63;
    const int start = node_start[wid];
    const int end = start + node_cnt[wid];
    const int head = lane >> 4;

    const float adv = alpha_d[wid * 4 + head];

    float a0x = 0.f, a0y = 0.f, a1x = 0.f, a1y = 0.f;
    float a2x = 0.f, a2y = 0.f, a3x = 0.f, a3y = 0.f;
    int i = start;
    for (; i + 7 < end; i += 8) {
        int s0 = srcs[i],     s1 = srcs[i + 1], s2 = srcs[i + 2], s3 = srcs[i + 3];
        int s4 = srcs[i + 4], s5 = srcs[i + 5], s6 = srcs[i + 6], s7 = srcs[i + 7];
        float t0 = alpha_s[s0 * 4 + head] + adv;
        float t1 = alpha_s[s1 * 4 + head] + adv;
        float t2 = alpha_s[s2 * 4 + head] + adv;
        float t3 = alpha_s[s3 * 4 + head] + adv;
        float t4 = alpha_s[s4 * 4 + head] + adv;
        float t5 = alpha_s[s5 * 4 + head] + adv;
        float t6 = alpha_s[s6 * 4 + head] + adv;
        float t7 = alpha_s[s7 * 4 + head] + adv;
        t0 = t0 > 0.f ? t0 : NEG_SLOPE * t0;
        t1 = t1 > 0.f ? t1 : NEG_SLOPE * t1;
        t2 = t2 > 0.f ? t2 : NEG_SLOPE * t2;
        t3 = t3 > 0.f ? t3 : NEG_SLOPE * t3;
        t4 = t4 > 0.f ? t4 : NEG_SLOPE * t4;
        t5 = t5 > 0.f ? t5 : NEG_SLOPE * t5;
        t6 = t6 > 0.f ? t6 : NEG_SLOPE * t6;
        t7 = t7 > 0.f ? t7 : NEG_SLOPE * t7;
        unsigned v0 = h32[(size_t)s0 * 64 + lane];
        unsigned v1 = h32[(size_t)s1 * 64 + lane];
        unsigned v2 = h32[(size_t)s2 * 64 + lane];
        unsigned v3 = h32[(size_t)s3 * 64 + lane];
        unsigned v4 = h32[(size_t)s4 * 64 + lane];
        unsigned v5 = h32[(size_t)s5 * 64 + lane];
        unsigned v6 = h32[(size_t)s6 * 64 + lane];
        unsigned v7 = h32[(size_t)s7 * 64 + lane];
        a0x = fmaf(t0, bf_lo(v0), a0x); a0y = fmaf(t0, bf_hi(v0), a0y);
        a1x = fmaf(t1, bf_lo(v1), a1x); a1y = fmaf(t1, bf_hi(v1), a1y);
        a2x = fmaf(t2, bf_lo(v2), a2x); a2y = fmaf(t2, bf_hi(v2), a2y);
        a3x = fmaf(t3, bf_lo(v3), a3x); a3y = fmaf(t3, bf_hi(v3), a3y);
        a0x = fmaf(t4, bf_lo(v4), a0x); a0y = fmaf(t4, bf_hi(v4), a0y);
        a1x = fmaf(t5, bf_lo(v5), a1x); a1y = fmaf(t5, bf_hi(v5), a1y);
        a2x = fmaf(t6, bf_lo(v6), a2x); a2y = fmaf(t6, bf_hi(v6), a2y);
        a3x = fmaf(t7, bf_lo(v7), a3x); a3y = fmaf(t7, bf_hi(v7), a3y);
    }
    for (; i + 1 < end; i += 2) {
        int s0 = srcs[i], s1 = srcs[i + 1];
        float t0 = alpha_s[s0 * 4 + head] + adv;
        float t1 = alpha_s[s1 * 4 + head] + adv;
        t0 = t0 > 0.f ? t0 : NEG_SLOPE * t0;
        t1 = t1 > 0.f ? t1 : NEG_SLOPE * t1;
        unsigned v0 = h32[(size_t)s0 * 64 + lane];
        unsigned v1 = h32[(size_t)s1 * 64 + lane];
        a0x = fmaf(t0, bf_lo(v0), a0x); a0y = fmaf(t0, bf_hi(v0), a0y);
        a1x = fmaf(t1, bf_lo(v1), a1x); a1y = fmaf(t1, bf_hi(v1), a1y);
    }
    if (i < end) {
        int s0 = srcs[i];
        float t0 = alpha_s[s0 * 4 + head] + adv;
        t0 = t0 > 0.f ? t0 : NEG_SLOPE * t0;
        unsigned v0 = h32[(size_t)s0 * 64 + lane];
        a2x = fmaf(t0, bf_lo(v0), a2x); a2y = fmaf(t0, bf_hi(v0), a2y);
    }
    float2 r = {(a0x + a1x) + (a2x + a3x), (a0y + a1y) + (a2y + a3y)};
    ((float2*)out)[(size_t)wid * 64 + lane] = r;
}

// ---------------------------------------------------------------------------
// Fallback atomic edge kernel (only if ws_size too small for the sort path).
// ---------------------------------------------------------------------------
__global__ __launch_bounds__(256) void edge_kernel(
    const int* __restrict__ ei,
    const unsigned* __restrict__ h32,
    const float* __restrict__ alpha_s, const float* __restrict__ alpha_d,
    float* __restrict__ out)
{
    const unsigned total = (unsigned)N_EDGES * 32u;
    const unsigned stride = gridDim.x * blockDim.x;
    for (unsigned i = blockIdx.x * blockDim.x + threadIdx.x; i < total; i += stride) {
        const int e = (int)(i >> 5);
        const int c = (int)(i & 31);
        const int src = ei[e];
        const int dst = ei[N_EDGES + e];
        const int head = c >> 3;

        float att = alpha_s[src * 4 + head] + alpha_d[dst * 4 + head];
        att = att > 0.f ? att : NEG_SLOPE * att;

        unsigned v0 = h32[(size_t)src * 64 + c * 2];
        unsigned v1 = h32[(size_t)src * 64 + c * 2 + 1];
        float* po = out + (size_t)dst * 128 + c * 4;
        atomicAdd(po + 0, att * bf_lo(v0));
        atomicAdd(po + 1, att * bf_hi(v0));
        atomicAdd(po + 2, att * bf_lo(v1));
        atomicAdd(po + 3, att * bf_hi(v1));
    }
}

extern "C" void kernel_launch(void* const* d_in, const int* in_sizes, int n_in,
                              void* d_out, int out_size, void* d_ws, size_t ws_size,
                              hipStream_t stream) {
    const float* x  = (const float*)d_in[0];
    const int*   ei = (const int*)d_in[1];
    const float* W  = (const float*)d_in[2];
    const float* a  = (const float*)d_in[3];
    float* out = (float*)d_out;

    // Workspace layout (~26 MB total):
    //   hb      12.8 MB | alpha_s/d 1.6 MB | part 7.5 MB | srcs16 3.75 MB |
    //   gcursor 512 i32 | node_start/cnt 0.4 MB | wbf 32 KB
    unsigned short* hb = (unsigned short*)d_ws;
    float* as = (float*)(hb + (size_t)N_NODES * 128);
    float* ad = as + (size_t)N_NODES * 4;
    unsigned* part = (unsigned*)(ad + (size_t)N_NODES * 4);
    unsigned short* srcs16 = (unsigned short*)(part + (size_t)NB * CAP);
    int* gcursor = (int*)(srcs16 + (size_t)NB * CAP);
    int* node_start = gcursor + 512;
    int* node_cnt   = node_start + 50176;
    unsigned short* wbf = (unsigned short*)(node_cnt + 50176);
    const size_t needed = (size_t)((char*)(wbf + 16384) - (char*)d_ws);

    prep_kernel<<<64, 256, 0, stream>>>(W, wbf, gcursor);

    if (ws_size >= needed) {
        fused_gp_kernel<<<GEMM_BLOCKS + PART_BLOCKS, 256, 0, stream>>>(
            x, wbf, a, hb, as, ad, ei, gcursor, part);
        bucket_kernel<<<NB, 256, 0, stream>>>(gcursor, part, srcs16, node_start, node_cnt);
        gather_kernel<<<(N_NODES * 64 + 255) / 256, 256, 0, stream>>>(
            srcs16, node_start, node_cnt, (const unsigned*)hb, as, ad, out);
    } else {
        fused_gp_kernel<<<GEMM_BLOCKS, 256, 0, stream>>>(
            x, wbf, a, hb, as, ad, ei, gcursor, part);
        hipMemsetAsync(d_out, 0, (size_t)out_size * sizeof(float), stream);
        edge_kernel<<<4096, 256, 0, stream>>>(ei, (const unsigned*)hb, as, ad, out);
    }
}